// Round 9
// baseline (127.075 us; speedup 1.0000x reference)
//
#include <hip/hip_runtime.h>
#include <hip/hip_bf16.h>
#include <math.h>

#define NN 256
#define DD 128
#define EE 64

typedef __attribute__((ext_vector_type(8))) short short8;
typedef __attribute__((ext_vector_type(4))) float f32x4;

static __device__ __forceinline__ unsigned short f2bf(float f) {
    __hip_bfloat16 b = __float2bfloat16(f);
    return *reinterpret_cast<unsigned short*>(&b);
}

static __device__ __forceinline__ float sigm(float l) {
    return __fdividef(1.f, 1.f + __expf(-l));
}

// bf16 B-fragment for mfma_16x16x32 from row-major f32 B[K][128] in global.
static __device__ __forceinline__ short8 ldb(const float* __restrict__ B, int kbase, int d) {
    unsigned short tmp[8];
    #pragma unroll
    for (int j = 0; j < 8; ++j) tmp[j] = f2bf(B[(kbase + j) * DD + d]);
    return *(const short8*)tmp;
}

// ---------------- Fused kernel: gate + aggregation + update MLP + LN --------
// R20: 2 rows per 512-thread block (grid 1024).  Waves 0-3 run row 2*blk,
// waves 4-7 run row 2*blk+1 — each 4-wave group is EXACTLY the verified R16
// single-stream pipeline (R17/R19's dual-accumulator ILP variants both
// regressed via spill: refuted).  Rationale (counter arithmetic): every R16
// block re-streamed W1+W2+U1+U2 = 325 KB from L2 (666 MB total ~ 19us of L2
// occupancy) and CUs serialized 8 blocks at ~12 resident waves.  2 rows per
// block halves both, and 34.8 KB LDS -> 4 blocks/CU = 32 waves (CU cap).
// Different per-row njt vs shared __syncthreads: loop runs to njtmax
// (block-uniform); inactive groups skip build/epi via GROUP-UNIFORM guards;
// barriers unconditional; ring reads unconditional (in-bounds <= 8192 B).
// Per-lane live set unchanged from R16 (VGPR 44 there; spills forbidden).
__global__ __launch_bounds__(512, 4)
void ecgc_fused(const float* __restrict__ h_g,
                const float* __restrict__ ef_g,
                const int*   __restrict__ mask_g,
                const float* __restrict__ W1_g,
                const float* __restrict__ b1_g,
                const float* __restrict__ W2_g,
                const float* __restrict__ b2_g,
                const float* __restrict__ U1_g,
                const float* __restrict__ b3_g,
                const float* __restrict__ U2_g,
                const float* __restrict__ b4_g,
                const float* __restrict__ gam_g,
                const float* __restrict__ bet_g,
                float*       __restrict__ out_g)
{
    const int tg   = threadIdx.x;
    const int g    = tg >> 8;          // row-group 0/1
    const int tl   = tg & 255;         // thread within group
    const int bi   = blockIdx.x * 2 + g;
    const int lane = tg & 63;
    const int wr   = (tg >> 6) & 3;    // wave within row-group
    const int m16  = lane & 15;
    const int quad = lane >> 4;
    // build-role indices: thread owns (j = bj, e = beb..beb+3) within group
    const int bj   = tl & 15;
    const int beb  = (tl >> 4) << 2;

    __shared__ __align__(16) float sh_ef4[2][NN * 4];   // 8 KB; reused as sh_p
    __shared__ __align__(16) float sh_q4[2][EE * 4];    // 2 KB
    __shared__ float sh_basep[2][4 * EE];               // 2 KB
    __shared__ float sh_w1e[3 * EE];                    // shared: W1 e-rows
    __shared__ int   sh_jlist[2][NN];                   // 2 KB
    __shared__ int   sh_wcnt[2][4], sh_cnt[2];
    __shared__ __align__(16) unsigned short sh_P[2][4][16 * EE];  // 16 KB rings
    __shared__ __align__(16) float sh_x[2][384];        // [h | mean | amax]
    __shared__ float sh_y[2][DD];
    __shared__ float sh_red[2][4];

    // ---- stage (per group unless noted) ----
    if (tl < DD) sh_x[g][tl] = h_g[(size_t)bi * DD + tl];
    {
        const float* efr = ef_g + (size_t)bi * NN * 3;
        sh_ef4[g][tl * 4 + 0] = efr[tl * 3 + 0];
        sh_ef4[g][tl * 4 + 1] = efr[tl * 3 + 1];
        sh_ef4[g][tl * 4 + 2] = efr[tl * 3 + 2];
        sh_ef4[g][tl * 4 + 3] = 0.f;
    }
    if (tg < 192) sh_w1e[tg] = W1_g[(DD + (tg >> 6)) * EE + (tg & 63)];  // shared

    const int mk = (mask_g[(size_t)bi * NN + tl] != 0) ? 1 : 0;
    const unsigned long long bal = __ballot(mk);   // wave = one group's 64 j's
    if (lane == 0) sh_wcnt[g][wr] = __popcll(bal);
    const int pre = __popcll(bal & ((1ull << lane) - 1ull));

    // basep: thread (e = tl&63) partial over d-range [wr*32, wr*32+32)
    {
        const int e = tl & 63;
        float acc = 0.f;
        #pragma unroll 8
        for (int d = wr * 32; d < wr * 32 + 32; ++d)
            acc = fmaf(h_g[(size_t)bi * DD + d], W1_g[d * EE + e], acc);
        sh_basep[g][wr * EE + e] = acc;
    }

    // W2 B-fragments; b2 for C-init; h_d and sign-flip per d-tile
    const int dstripe = wr * 32;
    short8 bfrag[2][2];
    float  nb2[2], hd2[2], flip[2];
    #pragma unroll
    for (int dt = 0; dt < 2; ++dt) {
        const int d = dstripe + 16 * dt + m16;
        nb2[dt] = b2_g[d];
        hd2[dt] = h_g[(size_t)bi * DD + d];
        flip[dt] = (hd2[dt] >= 0.f) ? 1.f : -1.f;
        #pragma unroll
        for (int kh = 0; kh < 2; ++kh)
            bfrag[dt][kh] = ldb(W2_g, kh * 32 + quad * 8, d);
    }
    __syncthreads();   // barrier 1: wcnt/basep/w1e ready

    {
        int wbase = 0;
        for (int ww = 0; ww < wr; ++ww) wbase += sh_wcnt[g][ww];
        if (mk) sh_jlist[g][wbase + pre] = tl;
        if (tl == 0)
            sh_cnt[g] = sh_wcnt[g][0] + sh_wcnt[g][1] + sh_wcnt[g][2] + sh_wcnt[g][3];
    }
    if (tl < EE) {
        const float base = b1_g[tl] + sh_basep[g][tl] + sh_basep[g][EE + tl] +
                           sh_basep[g][2 * EE + tl] + sh_basep[g][3 * EE + tl];
        sh_q4[g][tl * 4 + 0] = base;
        sh_q4[g][tl * 4 + 1] = sh_w1e[tl];
        sh_q4[g][tl * 4 + 2] = sh_w1e[EE + tl];
        sh_q4[g][tl * 4 + 3] = sh_w1e[2 * EE + tl];
    }
    __syncthreads();   // barrier 2: jlist/q4 ready (both groups)

    // build constants: this thread's 4 {base,w1e} rows (fixed e -> stays in reg)
    f32x4 qreg[4];
    #pragma unroll
    for (int i = 0; i < 4; ++i) qreg[i] = *(const f32x4*)&sh_q4[g][(beb + i) * 4];

    const int cnt  = sh_cnt[g];
    const int njt  = (cnt + 15) >> 4;
    const int njtmax = max((sh_cnt[0] + 15) >> 4, (sh_cnt[1] + 15) >> 4);  // uniform

    // swizzled LDS addressing (byte ^= ((row&7)<<4), bijective, b128-aligned)
    const int   sw_r = (m16 & 7) << 4;
    const char* prow = (const char*)&sh_P[g][0][m16 * EE];
    const int   offA = (quad * 16) ^ sw_r;        // kh=0: e 0..31
    const int   offB = (64 + quad * 16) ^ sw_r;   // kh=1: e 32..63
    char* pwr;
    {
        const int cb = 2 * beb;   // byte col of this thread's 4 e-values
        const int cs = (cb & 8) | ((((cb >> 4) ^ (bj & 7)) & 7) << 4);
        pwr = (char*)&sh_P[g][0][bj * EE] + cs;
    }

    float sum2[2] = {0.f, 0.f};
    float mm[2]   = {-3.0e38f, -3.0e38f};   // max over j of flip*logit

    auto buildP = [&](int jtile, int bufbyte) {
        const int row = jtile * 16 + bj;
        int jl = sh_jlist[g][row];
        jl = (row < cnt) ? jl : 0;              // clamp stale tail values
        const float4 efv = *(const float4*)&sh_ef4[g][jl * 4];
        float v[4];
        #pragma unroll
        for (int i = 0; i < 4; ++i)
            v[i] = fmaxf(fmaf(efv.z, qreg[i][3], fmaf(efv.y, qreg[i][2],
                         fmaf(efv.x, qreg[i][1], qreg[i][0]))), 0.f);
        union { __hip_bfloat162 h2; unsigned int u; } a0, a1;
        a0.h2 = __float22bfloat162_rn(make_float2(v[0], v[1]));
        a1.h2 = __float22bfloat162_rn(make_float2(v[2], v[3]));
        *reinterpret_cast<uint2*>(pwr + bufbyte) = make_uint2(a0.u, a1.u);
    };

    if (njt > 0) buildP(0, 0);        // group-uniform guards, no barrier inside
    if (njt > 1) buildP(1, 2048);
    __syncthreads();   // barrier 3: tiles 0,1 built (both groups)

    for (int jt = 0; jt < njtmax; ++jt) {
        const bool act = (jt < njt);            // group-uniform
        const int  bo  = (jt & 3) << 11;        // 2048-byte slot stride, 4-ring
        // unconditional reads: always in-bounds within the group's 8KB ring
        const short8 ua = *(const short8*)(prow + bo + offA);
        const short8 ub = *(const short8*)(prow + bo + offB);

        // build tile jt+2 into its ring slot (overlaps MFMA+epilogue)
        if (jt + 2 < njt) buildP(jt + 2, ((jt + 2) & 3) << 11);

        if (act) {
            const bool tail = (jt == njt - 1) && (cnt & 15);
            #pragma unroll
            for (int dt = 0; dt < 2; ++dt) {
                f32x4 acc = {nb2[dt], nb2[dt], nb2[dt], nb2[dt]};
                acc = __builtin_amdgcn_mfma_f32_16x16x32_bf16(ua, bfrag[dt][0], acc, 0, 0, 0);
                acc = __builtin_amdgcn_mfma_f32_16x16x32_bf16(ub, bfrag[dt][1], acc, 0, 0, 0);
                if (!tail) {
                    #pragma unroll
                    for (int r = 0; r < 4; ++r) {
                        const float l = acc[r];
                        mm[dt] = fmaxf(mm[dt], l * flip[dt]);
                        sum2[dt] += sigm(l);
                    }
                } else {
                    #pragma unroll
                    for (int r = 0; r < 4; ++r) {
                        const bool v = (jt * 16 + quad * 4 + r) < cnt;
                        const float lx = v ? acc[r] : -3.0e38f;            // sigm -> 0
                        const float pf = v ? acc[r] * flip[dt] : -3.0e38f; // never wins max
                        mm[dt] = fmaxf(mm[dt], pf);
                        sum2[dt] += sigm(lx);
                    }
                }
            }
        }
        if (jt & 1) __syncthreads();   // unconditional at block scope (jt uniform)
    }

    // cross-quad reduce; sigmoid applied once on the extreme logit (monotone).
    // Results go straight into sh_x[g][128..383] = [mean | amax].
    #pragma unroll
    for (int dt = 0; dt < 2; ++dt) {
        float s = sum2[dt], M = mm[dt];
        s += __shfl_xor(s, 16, 64);  s += __shfl_xor(s, 32, 64);
        M  = fmaxf(M,  __shfl_xor(M, 16, 64));  M  = fmaxf(M,  __shfl_xor(M, 32, 64));
        if (quad == 0) {
            const int d = dstripe + 16 * dt + m16;
            const float hd = hd2[dt];
            float mean = 0.f, amax = 0.f;
            if (cnt > 0) {
                mean = hd * s * __fdividef(1.f, (float)cnt);
                amax = hd * sigm(flip[dt] * M);   // flip=+1: max l; flip=-1: min l
            }
            sh_x[g][128 + d] = mean;
            sh_x[g][256 + d] = amax;
        }
    }
    __syncthreads();   // x ready for both groups; sh_ef4/sh_P dead -> reuse

    float* sh_p = sh_ef4[g];   // 8 x 128 partial buffer (exactly 4 KB per group)

    // ---- layer1: y = relu(x @ U1 + b3).  x: 1x384, U1: 384x128 row-major.
    // thread: 4 consecutive e (float4 columns), 1/8 of the k-range.
    // Both groups read the SAME U1 addresses -> one L2 stream serves 2 rows.
    {
        const int e4 = (tl & 31) * 4;
        const int ks = (tl >> 5) * 48;
        f32x4 a = {0.f, 0.f, 0.f, 0.f};
        for (int kk = 0; kk < 48; ++kk) {
            const float  xk = sh_x[g][ks + kk];
            const float4 u  = *(const float4*)&U1_g[(size_t)(ks + kk) * DD + e4];
            a[0] = fmaf(xk, u.x, a[0]); a[1] = fmaf(xk, u.y, a[1]);
            a[2] = fmaf(xk, u.z, a[2]); a[3] = fmaf(xk, u.w, a[3]);
        }
        *(f32x4*)&sh_p[(tl >> 5) * DD + e4] = a;
    }
    __syncthreads();
    if (tl < DD) {
        float y = b3_g[tl];
        #pragma unroll
        for (int s = 0; s < 8; ++s) y += sh_p[s * DD + tl];
        sh_y[g][tl] = fmaxf(y, 0.f);
    }
    __syncthreads();   // sh_y ready; sh_p consumers done

    // ---- layer2: z = y @ U2 + b4; xv = h + z ----
    {
        const int d4 = (tl & 31) * 4;
        const int es = (tl >> 5) * 16;
        f32x4 a = {0.f, 0.f, 0.f, 0.f};
        for (int ee = 0; ee < 16; ++ee) {
            const float  ye = sh_y[g][es + ee];
            const float4 u  = *(const float4*)&U2_g[(size_t)(es + ee) * DD + d4];
            a[0] = fmaf(ye, u.x, a[0]); a[1] = fmaf(ye, u.y, a[1]);
            a[2] = fmaf(ye, u.z, a[2]); a[3] = fmaf(ye, u.w, a[3]);
        }
        *(f32x4*)&sh_p[(tl >> 5) * DD + d4] = a;
    }
    __syncthreads();

    // ---- combine + residual + LayerNorm (rows tl<128 = group waves 0,1) ----
    float xv = 0.f;
    if (tl < DD) {
        xv = sh_x[g][tl] + b4_g[tl];
        #pragma unroll
        for (int s = 0; s < 8; ++s) xv += sh_p[s * DD + tl];
        float s1 = xv, s2v = xv * xv;
        #pragma unroll
        for (int off = 1; off < 64; off <<= 1) {
            s1  += __shfl_xor(s1,  off, 64);
            s2v += __shfl_xor(s2v, off, 64);
        }
        const int wrl = (tl >> 6);   // 0 or 1
        if (lane == 0) { sh_red[g][2 * wrl] = s1; sh_red[g][2 * wrl + 1] = s2v; }
    }
    __syncthreads();
    if (tl < DD) {
        const float S   = sh_red[g][0] + sh_red[g][2];
        const float S2  = sh_red[g][1] + sh_red[g][3];
        const float mu  = S * (1.f / 128.f);
        const float var = S2 * (1.f / 128.f) - mu * mu;
        const float rs  = rsqrtf(var + 1e-5f);
        out_g[(size_t)bi * DD + tl] = (xv - mu) * rs * gam_g[tl] + bet_g[tl];
    }
}

extern "C" void kernel_launch(void* const* d_in, const int* in_sizes, int n_in,
                              void* d_out, int out_size, void* d_ws, size_t ws_size,
                              hipStream_t stream) {
    (void)d_ws; (void)ws_size;
    ecgc_fused<<<4 * NN, 512, 0, stream>>>(   // 1024 blocks x 512 threads, 2 rows/block
        (const float*)d_in[0],   // h
        (const float*)d_in[1],   // edge_feats
        (const int*)d_in[2],     // adj_mask
        (const float*)d_in[3],   // W1
        (const float*)d_in[4],   // b1
        (const float*)d_in[5],   // W2
        (const float*)d_in[6],   // b2
        (const float*)d_in[7],   // U1
        (const float*)d_in[8],   // b3
        (const float*)d_in[9],   // U2
        (const float*)d_in[10],  // b4
        (const float*)d_in[11],  // gamma
        (const float*)d_in[12],  // beta
        (float*)d_out);
}

// Round 10
// 117.823 us; speedup vs baseline: 1.0785x; 1.0785x over previous
//
#include <hip/hip_runtime.h>
#include <hip/hip_bf16.h>
#include <math.h>

#define NN 256
#define DD 128
#define EE 64

typedef __attribute__((ext_vector_type(8))) short short8;
typedef __attribute__((ext_vector_type(4))) float f32x4;

static __device__ __forceinline__ unsigned short f2bf(float f) {
    __hip_bfloat16 b = __float2bfloat16(f);
    return *reinterpret_cast<unsigned short*>(&b);
}

static __device__ __forceinline__ float sigm(float l) {
    return __fdividef(1.f, 1.f + __expf(-l));
}

// bf16 B-fragment for mfma_16x16x32 from row-major f32 B[K][128] in global.
static __device__ __forceinline__ short8 ldb(const float* __restrict__ B, int kbase, int d) {
    unsigned short tmp[8];
    #pragma unroll
    for (int j = 0; j < 8; ++j) tmp[j] = f2bf(B[(kbase + j) * DD + d]);
    return *(const short8*)tmp;
}

// ---------------- Fused kernel: gate + aggregation + update MLP + LN --------
// R21 == R16 verbatim (the session's best verified kernel: 44.7-46.9us over
// three profiled rounds, VGPR 44, no spill).  Restored after R20's 2-row
// merge regressed (52-54us: wider barrier scope + njtmax convoy; weight
// amortization bought nothing).  Evidence summary across the session:
// four structures converge to 42-46us kernel time; per-wave ILP (R17/R19)
// spilled, j-ownership register blocking (R13) spilled, row-merge (R20)
// regressed, barrier-halving (R14) neutral.  The floor is the per-(i,j,d)
// sigmoid/max/sum epilogue + per-(i,j,e) build at ~60% achievable VALU
// issue; remaining headroom ~10us vs ~73us fixed harness overhead.
__global__ __launch_bounds__(256, 4)
void ecgc_fused(const float* __restrict__ h_g,
                const float* __restrict__ ef_g,
                const int*   __restrict__ mask_g,
                const float* __restrict__ W1_g,
                const float* __restrict__ b1_g,
                const float* __restrict__ W2_g,
                const float* __restrict__ b2_g,
                const float* __restrict__ U1_g,
                const float* __restrict__ b3_g,
                const float* __restrict__ U2_g,
                const float* __restrict__ b4_g,
                const float* __restrict__ gam_g,
                const float* __restrict__ bet_g,
                float*       __restrict__ out_g)
{
    const int bi   = blockIdx.x;
    const int t    = threadIdx.x;
    const int lane = t & 63;
    const int w    = t >> 6;
    const int m16  = lane & 15;
    const int quad = lane >> 4;
    // build-role indices: thread owns (j = bj, e = beb..beb+3)
    const int bj   = t & 15;
    const int beb  = (t >> 4) << 2;

    __shared__ __align__(16) float sh_ef4[NN * 4];   // 4 KB; reused as sh_p after j-loop
    __shared__ __align__(16) float sh_q4[EE * 4];    // 1 KB {base,w10,w11,w12}
    __shared__ float sh_basep[4 * EE];               // 1 KB
    __shared__ float sh_w1e[3 * EE];
    __shared__ int   sh_jlist[NN], sh_wcnt[4], sh_cnt;
    __shared__ __align__(16) unsigned short sh_P[4][16 * EE];  // 8 KB ring, swizzled
    __shared__ __align__(16) float sh_x[384];        // [h | mean | amax]
    __shared__ float sh_y[DD];
    __shared__ float sh_red[4];

    // ---- stage ----
    if (t < DD) sh_x[t] = h_g[bi * DD + t];
    {
        const float* efr = ef_g + (size_t)bi * NN * 3;
        sh_ef4[t * 4 + 0] = efr[t * 3 + 0];
        sh_ef4[t * 4 + 1] = efr[t * 3 + 1];
        sh_ef4[t * 4 + 2] = efr[t * 3 + 2];
        sh_ef4[t * 4 + 3] = 0.f;
    }
    if (t < 192) sh_w1e[t] = W1_g[(DD + (t >> 6)) * EE + (t & 63)];

    const int mk = (mask_g[bi * NN + t] != 0) ? 1 : 0;
    const unsigned long long bal = __ballot(mk);
    if (lane == 0) sh_wcnt[w] = __popcll(bal);
    const int pre = __popcll(bal & ((1ull << lane) - 1ull));

    // basep: thread (e = t&63) partial over d-range [w*32, w*32+32)
    {
        const int e = t & 63;
        float acc = 0.f;
        #pragma unroll 8
        for (int d = w * 32; d < w * 32 + 32; ++d)
            acc = fmaf(h_g[bi * DD + d], W1_g[d * EE + e], acc);
        sh_basep[w * EE + e] = acc;
    }

    // W2 B-fragments; b2 for C-init; h_d and sign-flip per d-tile
    const int dstripe = w * 32;
    short8 bfrag[2][2];
    float  nb2[2], hd2[2], flip[2];
    #pragma unroll
    for (int dt = 0; dt < 2; ++dt) {
        const int d = dstripe + 16 * dt + m16;
        nb2[dt] = b2_g[d];
        hd2[dt] = h_g[bi * DD + d];
        flip[dt] = (hd2[dt] >= 0.f) ? 1.f : -1.f;
        #pragma unroll
        for (int kh = 0; kh < 2; ++kh)
            bfrag[dt][kh] = ldb(W2_g, kh * 32 + quad * 8, d);
    }
    __syncthreads();   // barrier 1: wcnt/basep/w1e ready

    {
        int wbase = 0;
        for (int ww = 0; ww < w; ++ww) wbase += sh_wcnt[ww];
        if (mk) sh_jlist[wbase + pre] = t;
        if (t == 0) sh_cnt = sh_wcnt[0] + sh_wcnt[1] + sh_wcnt[2] + sh_wcnt[3];
    }
    if (t < EE) {
        const float base = b1_g[t] + sh_basep[t] + sh_basep[EE + t] +
                           sh_basep[2 * EE + t] + sh_basep[3 * EE + t];
        sh_q4[t * 4 + 0] = base;
        sh_q4[t * 4 + 1] = sh_w1e[t];
        sh_q4[t * 4 + 2] = sh_w1e[EE + t];
        sh_q4[t * 4 + 3] = sh_w1e[2 * EE + t];
    }
    __syncthreads();   // barrier 2: jlist/q4 ready

    // build constants: this thread's 4 {base,w1e} rows (fixed e -> stays in reg)
    f32x4 qreg[4];
    #pragma unroll
    for (int i = 0; i < 4; ++i) qreg[i] = *(const f32x4*)&sh_q4[(beb + i) * 4];

    const int cnt = sh_cnt;
    const int njt = (cnt + 15) >> 4;

    // swizzled LDS addressing (byte ^= ((row&7)<<4), bijective, b128-aligned)
    const int   sw_r = (m16 & 7) << 4;
    const char* prow = (const char*)&sh_P[0][m16 * EE];
    const int   offA = (quad * 16) ^ sw_r;        // kh=0: e 0..31
    const int   offB = (64 + quad * 16) ^ sw_r;   // kh=1: e 32..63
    char* pwr;
    {
        const int cb = 2 * beb;   // byte col of this thread's 4 e-values
        const int cs = (cb & 8) | ((((cb >> 4) ^ (bj & 7)) & 7) << 4);
        pwr = (char*)&sh_P[0][bj * EE] + cs;
    }

    float sum2[2] = {0.f, 0.f};
    float mm[2]   = {-3.0e38f, -3.0e38f};   // max over j of flip*logit

    auto buildP = [&](int jtile, int bufbyte) {
        const int row = jtile * 16 + bj;
        int jl = sh_jlist[row];
        jl = (row < cnt) ? jl : 0;              // clamp stale tail values
        const float4 efv = *(const float4*)&sh_ef4[jl * 4];
        float v[4];
        #pragma unroll
        for (int i = 0; i < 4; ++i)
            v[i] = fmaxf(fmaf(efv.z, qreg[i][3], fmaf(efv.y, qreg[i][2],
                         fmaf(efv.x, qreg[i][1], qreg[i][0]))), 0.f);
        union { __hip_bfloat162 h2; unsigned int u; } a0, a1;
        a0.h2 = __float22bfloat162_rn(make_float2(v[0], v[1]));
        a1.h2 = __float22bfloat162_rn(make_float2(v[2], v[3]));
        *reinterpret_cast<uint2*>(pwr + bufbyte) = make_uint2(a0.u, a1.u);
    };

    if (njt > 0) buildP(0, 0);
    if (njt > 1) buildP(1, 2048);
    __syncthreads();   // barrier 3: tiles 0,1 built

    for (int jt = 0; jt < njt; ++jt) {
        const int bo = (jt & 3) << 11;          // 2048-byte slot stride, 4-ring
        const short8 ua = *(const short8*)(prow + bo + offA);
        const short8 ub = *(const short8*)(prow + bo + offB);

        // build tile jt+2 into its ring slot (overlaps MFMA+epilogue)
        if (jt + 2 < njt) buildP(jt + 2, ((jt + 2) & 3) << 11);

        const bool tail = (jt == njt - 1) && (cnt & 15);
        #pragma unroll
        for (int dt = 0; dt < 2; ++dt) {
            f32x4 acc = {nb2[dt], nb2[dt], nb2[dt], nb2[dt]};
            acc = __builtin_amdgcn_mfma_f32_16x16x32_bf16(ua, bfrag[dt][0], acc, 0, 0, 0);
            acc = __builtin_amdgcn_mfma_f32_16x16x32_bf16(ub, bfrag[dt][1], acc, 0, 0, 0);
            if (!tail) {
                #pragma unroll
                for (int r = 0; r < 4; ++r) {
                    const float l = acc[r];
                    mm[dt] = fmaxf(mm[dt], l * flip[dt]);
                    sum2[dt] += sigm(l);
                }
            } else {
                #pragma unroll
                for (int r = 0; r < 4; ++r) {
                    const bool v = (jt * 16 + quad * 4 + r) < cnt;
                    const float lx = v ? acc[r] : -3.0e38f;            // sigm -> 0
                    const float pf = v ? acc[r] * flip[dt] : -3.0e38f; // never wins max
                    mm[dt] = fmaxf(mm[dt], pf);
                    sum2[dt] += sigm(lx);
                }
            }
        }
        if (jt & 1) __syncthreads();   // barrier every 2 tiles (ring-window safe)
    }

    // cross-quad reduce; sigmoid applied once on the extreme logit (monotone).
    // Results go straight into sh_x[128..383] = [mean | amax].
    #pragma unroll
    for (int dt = 0; dt < 2; ++dt) {
        float s = sum2[dt], M = mm[dt];
        s += __shfl_xor(s, 16, 64);  s += __shfl_xor(s, 32, 64);
        M  = fmaxf(M,  __shfl_xor(M, 16, 64));  M  = fmaxf(M,  __shfl_xor(M, 32, 64));
        if (quad == 0) {
            const int d = dstripe + 16 * dt + m16;
            const float hd = hd2[dt];
            float mean = 0.f, amax = 0.f;
            if (cnt > 0) {
                mean = hd * s * __fdividef(1.f, (float)cnt);
                amax = hd * sigm(flip[dt] * M);   // flip=+1: max l; flip=-1: min l
            }
            sh_x[128 + d] = mean;
            sh_x[256 + d] = amax;
        }
    }
    __syncthreads();   // x = [h|mean|amax] ready; sh_ef4/sh_P dead -> reuse

    float* sh_p = sh_ef4;   // 8 x 128 partial buffer (exactly 4 KB)

    // ---- layer1: y = relu(x @ U1 + b3).  x: 1x384, U1: 384x128 row-major.
    // thread: 4 consecutive e (float4 columns), 1/8 of the k-range.
    {
        const int e4 = (t & 31) * 4;
        const int ks = (t >> 5) * 48;
        f32x4 a = {0.f, 0.f, 0.f, 0.f};
        for (int kk = 0; kk < 48; ++kk) {
            const float  xk = sh_x[ks + kk];
            const float4 u  = *(const float4*)&U1_g[(size_t)(ks + kk) * DD + e4];
            a[0] = fmaf(xk, u.x, a[0]); a[1] = fmaf(xk, u.y, a[1]);
            a[2] = fmaf(xk, u.z, a[2]); a[3] = fmaf(xk, u.w, a[3]);
        }
        *(f32x4*)&sh_p[(t >> 5) * DD + e4] = a;
    }
    __syncthreads();
    if (t < DD) {
        float y = b3_g[t];
        #pragma unroll
        for (int s = 0; s < 8; ++s) y += sh_p[s * DD + t];
        sh_y[t] = fmaxf(y, 0.f);
    }
    __syncthreads();   // sh_y ready; sh_p consumers done

    // ---- layer2: z = y @ U2 + b4; xv = h + z ----
    {
        const int d4 = (t & 31) * 4;
        const int es = (t >> 5) * 16;
        f32x4 a = {0.f, 0.f, 0.f, 0.f};
        for (int ee = 0; ee < 16; ++ee) {
            const float  ye = sh_y[es + ee];
            const float4 u  = *(const float4*)&U2_g[(size_t)(es + ee) * DD + d4];
            a[0] = fmaf(ye, u.x, a[0]); a[1] = fmaf(ye, u.y, a[1]);
            a[2] = fmaf(ye, u.z, a[2]); a[3] = fmaf(ye, u.w, a[3]);
        }
        *(f32x4*)&sh_p[(t >> 5) * DD + d4] = a;
    }
    __syncthreads();

    // ---- combine + residual + LayerNorm (rows t<128 live in waves 0,1) ----
    float xv = 0.f;
    if (t < DD) {
        xv = sh_x[t] + b4_g[t];
        #pragma unroll
        for (int s = 0; s < 8; ++s) xv += sh_p[s * DD + t];
        float s1 = xv, s2v = xv * xv;
        #pragma unroll
        for (int off = 1; off < 64; off <<= 1) {
            s1  += __shfl_xor(s1,  off, 64);
            s2v += __shfl_xor(s2v, off, 64);
        }
        if (lane == 0) { sh_red[2 * w] = s1; sh_red[2 * w + 1] = s2v; }
    }
    __syncthreads();
    if (t < DD) {
        const float S   = sh_red[0] + sh_red[2];
        const float S2  = sh_red[1] + sh_red[3];
        const float mu  = S * (1.f / 128.f);
        const float var = S2 * (1.f / 128.f) - mu * mu;
        const float rs  = rsqrtf(var + 1e-5f);
        out_g[(size_t)bi * DD + t] = (xv - mu) * rs * gam_g[t] + bet_g[t];
    }
}

extern "C" void kernel_launch(void* const* d_in, const int* in_sizes, int n_in,
                              void* d_out, int out_size, void* d_ws, size_t ws_size,
                              hipStream_t stream) {
    (void)d_ws; (void)ws_size;
    ecgc_fused<<<8 * NN, 256, 0, stream>>>(
        (const float*)d_in[0],   // h
        (const float*)d_in[1],   // edge_feats
        (const int*)d_in[2],     // adj_mask
        (const float*)d_in[3],   // W1
        (const float*)d_in[4],   // b1
        (const float*)d_in[5],   // W2
        (const float*)d_in[6],   // b2
        (const float*)d_in[7],   // U1
        (const float*)d_in[8],   // b3
        (const float*)d_in[9],   // U2
        (const float*)d_in[10],  // b4
        (const float*)d_in[11],  // gamma
        (const float*)d_in[12],  // beta
        (float*)d_out);
}